// Round 1
// 529.646 us; speedup vs baseline: 1.0390x; 1.0390x over previous
//
#include <hip/hip_runtime.h>

typedef unsigned short u16;
typedef unsigned int   u32;
typedef unsigned long long u64;
typedef float  f32x4  __attribute__((ext_vector_type(4)));
typedef __bf16 bf16x8 __attribute__((ext_vector_type(8)));

#define DEV static __device__ __forceinline__

DEV float bf2f(u16 u){ union{float f;u32 i;}v; v.i=((u32)u)<<16; return v.f; }
DEV float bflo(u32 u){ union{float f;u32 i;}v; v.i=u<<16; return v.f; }
DEV float bfhi(u32 u){ union{float f;u32 i;}v; v.i=u&0xffff0000u; return v.f; }
DEV u16   f2bf(float f){ union{float f;u32 i;}v; v.f=f; return (u16)((v.i + 0x7fffu + ((v.i>>16)&1u))>>16); }

DEV void async16(const void* g, void* l){
  __builtin_amdgcn_global_load_lds((const __attribute__((address_space(1))) void*)g,
                                   (__attribute__((address_space(3))) void*)l, 16, 0, 0);
}

// ---------------- cast fp32 -> bf16 (4 elems/thread) ----------------
__global__ __launch_bounds__(256) void cast_bf16(const float* __restrict__ in,
                                                 u16* __restrict__ out, int n4)
{
  int i = blockIdx.x*256 + threadIdx.x;
  if (i >= n4) return;
  float4 v = ((const float4*)in)[i];
  ushort4 o;
  o.x = f2bf(v.x); o.y = f2bf(v.y); o.z = f2bf(v.z); o.w = f2bf(v.w);
  ((ushort4*)out)[i] = o;
}

// ---------------- bf16 MFMA GEMM, 256x256 tile, 8-phase counted-vmcnt schedule ----------------
// C[m][n] = sum_k A[m][k]*W[n][k].  512 threads = 8 waves (2M x 4N), 128x64 C per wave.
// BK=64, double-buffered 128KiB LDS, source-side XOR chunk swizzle (same as verified 128^2
// kernel: zero bank conflicts), counted vmcnt(6) once per K-tile (T3+T4), setprio (T5).
//
// Staging safety ledger (per K-tile group T, reading buf[T&1]):
//   ph0: reads ALL A frags (mi0-3) + ALL B frags; stages (T+1,B-h1) -> buf[T^1]  (disjoint)
//   ph1: pure MFMA (bfr[2..3] consumed here -> drained by ph1-end barrier)
//   ph2: reads A frags mi4-7 (As only); stages (T+2,B-h0) -> Bs buf[T&1] (B reads drained ph1)
//   ph3: stages (T+2,A-h0),(T+2,A-h1) -> As buf[T&1] (A reads drained by ph2 lgkm+barrier)
//   group end: vmcnt(6) = exactly the 3 stages of ph2+ph3 in flight; tile T+1 fully landed.
__global__ __launch_bounds__(512, 2) void gemm256(
    const u16* __restrict__ A, const u16* __restrict__ W, int K, int mode,
    u16* __restrict__ oq, u16* __restrict__ okk, u16* __restrict__ ov,
    float* __restrict__ of, const float* __restrict__ bias)
{
  __shared__ __align__(16) u16 As[2*16384];   // 2 bufs x 256 rows x 64 (swizzled 16B chunks)
  __shared__ __align__(16) u16 Bs[2*16384];
  const int tid  = threadIdx.x;
  const int w = tid >> 6, lane = tid & 63;
  const int wm = w >> 2, wn = w & 3;          // 2 M-waves x 4 N-waves
  const int r16 = lane & 15, q4 = lane >> 4;
  const int xr = r16 & 7;
  const size_t Abase = (size_t)blockIdx.x * 256 * K;
  const size_t Bbase = (size_t)blockIdx.y * 256 * K;
  const int NT = K >> 6;

// one half-tile = 128 rows x 64 cols bf16 = 16KB = 512 thr x 2 x 16B
#define STAGE(t, half, arr) do { \
    const u16* _src = (arr) ? (W + Bbase) : (A + Abase); \
    u16* _dst = ((arr) ? Bs : As) + (((t) & 1) * 16384 + (half) * 8192); \
    const int _k0 = (t) << 6; \
    _Pragma("unroll") \
    for (int _i = 0; _i < 2; _i++) { \
      int _s = _i*512 + tid; \
      int _row = _s >> 3; \
      int _c = (_s & 7) ^ (_row & 7); \
      async16(_src + (size_t)((half)*128 + _row) * K + _k0 + _c*8, (char*)_dst + (size_t)_s * 16); \
    } \
  } while(0)

#define READ_A(MI0) do { \
    _Pragma("unroll") \
    for (int _i = 0; _i < 4; _i++) { \
      int _row = wm*128 + ((MI0)+_i)*16 + r16; \
      _Pragma("unroll") \
      for (int _ks = 0; _ks < 2; _ks++) \
        af[_i][_ks] = *(const bf16x8*)&As[boff + _row*64 + (((_ks*4 + q4) ^ xr) * 8)]; \
    } \
  } while(0)

#define READ_B() do { \
    _Pragma("unroll") \
    for (int _j = 0; _j < 4; _j++) { \
      int _row = wn*64 + _j*16 + r16; \
      _Pragma("unroll") \
      for (int _ks = 0; _ks < 2; _ks++) \
        bfr[_j][_ks] = *(const bf16x8*)&Bs[boff + _row*64 + (((_ks*4 + q4) ^ xr) * 8)]; \
    } \
  } while(0)

#define MFMA_Q(MI0, NI0) do { \
    _Pragma("unroll") \
    for (int _ks = 0; _ks < 2; _ks++) \
      _Pragma("unroll") \
      for (int _i = 0; _i < 4; _i++) \
        _Pragma("unroll") \
        for (int _j = 0; _j < 2; _j++) \
          acc[(MI0)+_i][(NI0)+_j] = __builtin_amdgcn_mfma_f32_16x16x32_bf16( \
              bfr[(NI0)+_j][_ks], af[_i][_ks], acc[(MI0)+_i][(NI0)+_j], 0,0,0); \
  } while(0)

  f32x4 acc[8][4];
  #pragma unroll
  for (int i=0;i<8;i++)
    #pragma unroll
    for (int j=0;j<4;j++) acc[i][j] = (f32x4){0.f,0.f,0.f,0.f};
  bf16x8 af[4][2], bfr[4][2];

  // ---- prologue: tile0 fully, tile1 {B-h0, A-h0, A-h1}; vmcnt(6) -> tile0 landed ----
  STAGE(0,0,0); STAGE(0,1,0); STAGE(0,0,1); STAGE(0,1,1);
  STAGE(1,0,1); STAGE(1,0,0); STAGE(1,1,0);
  asm volatile("s_waitcnt vmcnt(6)" ::: "memory");
  __builtin_amdgcn_s_barrier();

  for (int T = 0; T < NT; ++T) {
    const int boff = (T & 1) * 16384;
    // ---- ph0 ----
    READ_A(0);
    READ_B();
    if (T+1 < NT) STAGE(T+1, 1, 1);          // (T+1) B-h1 -> other buffer
    __builtin_amdgcn_s_barrier();
    asm volatile("s_waitcnt lgkmcnt(0)" ::: "memory");
    __builtin_amdgcn_sched_barrier(0);
    __builtin_amdgcn_s_setprio(1);
    MFMA_Q(0, 0);
    __builtin_amdgcn_s_setprio(0);
    __builtin_amdgcn_s_barrier();
    // ---- ph1 (pure MFMA) ----
    __builtin_amdgcn_s_setprio(1);
    MFMA_Q(0, 2);
    __builtin_amdgcn_s_setprio(0);
    __builtin_amdgcn_s_barrier();
    // ---- ph2 ----
    READ_A(4);
    if (T+2 < NT) STAGE(T+2, 0, 1);          // (T+2) B-h0 -> current buffer (B reads drained)
    __builtin_amdgcn_s_barrier();
    asm volatile("s_waitcnt lgkmcnt(0)" ::: "memory");
    __builtin_amdgcn_sched_barrier(0);
    __builtin_amdgcn_s_setprio(1);
    MFMA_Q(4, 0);
    __builtin_amdgcn_s_setprio(0);
    __builtin_amdgcn_s_barrier();
    // ---- ph3 ----
    if (T+2 < NT) { STAGE(T+2, 0, 0); STAGE(T+2, 1, 0); }  // (T+2) A-h0, A-h1
    __builtin_amdgcn_s_setprio(1);
    MFMA_Q(4, 2);
    __builtin_amdgcn_s_setprio(0);
    if (T+2 < NT)      asm volatile("s_waitcnt vmcnt(6)" ::: "memory");
    else if (T+1 < NT) asm volatile("s_waitcnt vmcnt(0)" ::: "memory");
    __builtin_amdgcn_s_barrier();
  }

#undef STAGE
#undef READ_A
#undef READ_B
#undef MFMA_Q

  // ---- epilogue: same fragment->C mapping as verified 128^2 kernel ----
  const int m0  = blockIdx.x*256 + wm*128;
  const int n0g = blockIdx.y*256 + wn*64;
  if (mode == 0){
    int sel = blockIdx.y >> 1;               // 256-n tiles never straddle q/k/v
    u16* dst = sel==0 ? oq : (sel==1 ? okk : ov);
    #pragma unroll
    for (int i=0;i<8;i++){
      int token = m0 + i*16 + r16;
      #pragma unroll
      for (int j=0;j<4;j++){
        int col = (n0g + j*16 + q4*4) & 511;
        uint2 pk;
        pk.x = (u32)f2bf(acc[i][j][0]) | ((u32)f2bf(acc[i][j][1]) << 16);
        pk.y = (u32)f2bf(acc[i][j][2]) | ((u32)f2bf(acc[i][j][3]) << 16);
        *(uint2*)&dst[(size_t)token*512 + col] = pk;
      }
    }
  } else {
    #pragma unroll
    for (int j=0;j<4;j++){
      int nbase = n0g + j*16 + q4*4;
      float4 b4 = *(const float4*)&bias[nbase];
      #pragma unroll
      for (int i=0;i<8;i++){
        int token = m0 + i*16 + r16;
        float4 o4 = { acc[i][j][0]+b4.x, acc[i][j][1]+b4.y,
                      acc[i][j][2]+b4.z, acc[i][j][3]+b4.w };
        *(float4*)&of[(size_t)token*512 + nbase] = o4;
      }
    }
  }
}

// ---------------- agent pooling: exact 8x8 block mean of q (64 padded slots) ----------------
__global__ __launch_bounds__(256) void pool_q(const u16* __restrict__ qb, u16* __restrict__ agentb)
{
  int idx = blockIdx.x*256 + threadIdx.x;          // 16*64*512
  int c = idx & 511;
  int ba = idx >> 9;
  int a = ba & 63, b = ba >> 6;
  if (a >= 49) { agentb[idx] = 0; return; }
  int ay = a / 7, ax = a % 7;
  const u16* base = qb + (size_t)b*3136*512 + c;
  float acc = 0.f;
  #pragma unroll
  for (int iy=0; iy<8; iy++){
    int rowoff = ((ay*8 + iy)*56 + ax*8) * 512;
    #pragma unroll
    for (int ix=0; ix<8; ix++) acc += bf2f(base[(size_t)rowoff + ix*512]);
  }
  agentb[idx] = f2bf(acc * 0.015625f);
}

// ---------------- bias tables: PB[8][49][196], AB[8][197][49] ----------------
DEV void lin1(float c, int S, int& i0, int& i1, float& w){
  if (c <= 0.f){ i0=0; i1=0; w=0.f; }
  else if (c >= (float)(S-1)){ i0=S-1; i1=S-1; w=0.f; }
  else { i0=(int)c; i1=i0+1; w=c-(float)i0; }
}
DEV float bilin7(const float* s, int Y, int X){
  int y0,y1,x0,x1; float wy,wx;
  lin1(0.5f*Y - 0.25f, 7, y0,y1,wy);
  lin1(0.5f*X - 0.25f, 7, x0,x1,wx);
  float v0 = s[y0*7+x0] + wx*(s[y0*7+x1]-s[y0*7+x0]);
  float v1 = s[y1*7+x0] + wx*(s[y1*7+x1]-s[y1*7+x0]);
  return v0 + wy*(v1 - v0);
}
__global__ __launch_bounds__(256) void bias_pre(
    const float* __restrict__ an_bias, const float* __restrict__ na_bias,
    const float* __restrict__ ah_bias, const float* __restrict__ aw_bias,
    const float* __restrict__ ha_bias, const float* __restrict__ wa_bias,
    const float* __restrict__ ca_bias, float* __restrict__ PB, float* __restrict__ AB)
{
  int idx = blockIdx.x*256 + threadIdx.x;
  if (idx < 8*49*196){
    int j = idx % 196; int ha = idx / 196; int a = ha % 49, h = ha / 49;
    int wy = j / 14, wx = j % 14;
    PB[idx] = bilin7(an_bias + (h*49+a)*49, wy, wx)
            + ah_bias[(h*49+a)*14 + wy] + aw_bias[(h*49+a)*14 + wx];
  }
  int idx2 = idx - 8*49*196;
  if (idx2 >= 0 && idx2 < 8*197*49){
    int a = idx2 % 49; int hr = idx2 / 49; int r = hr % 197, h = hr / 197;
    float v;
    if (r == 0) v = ca_bias[h*49 + a];
    else {
      int j = r - 1; int wy = j / 14, wx = j % 14;
      v = bilin7(na_bias + (h*49+a)*49, wy, wx)
        + ha_bias[(h*14+wy)*49 + a] + wa_bias[(h*14+wx)*49 + a];
    }
    AB[idx2] = v;
  }
}

// ---------------- merged bias expand: PBIT[h][n][64] and ABI[h][n][64] ----------------
__global__ __launch_bounds__(256) void bias_expand2(
    const float* __restrict__ PB, const float* __restrict__ AB,
    float* __restrict__ PBIT, float* __restrict__ ABI)
{
  int idx = blockIdx.x*256 + threadIdx.x;
  if (idx < 1605632) {
    int a = idx & 63; int t = idx >> 6; int n = t % 3136; int h = t / 3136;
    float val = -1e30f;
    if (a < 49) {
      const float* row = PB + (h*49 + a)*196;
      float c1 = (n + 0.5f)*0.0625f - 0.5f;
      if (c1 <= 0.f) val = row[0];
      else if (c1 >= 195.f) val = row[195];
      else { int j0 = (int)c1; float w = c1 - (float)j0; val = row[j0] + w*(row[j0+1]-row[j0]); }
    }
    PBIT[idx] = val;
  } else {
    int idx2 = idx - 1605632;
    if (idx2 >= 1605632) return;
    int a = idx2 & 63; int t = idx2 >> 6; int n = t % 3136; int h = t / 3136;
    float val = -1e30f;
    if (a < 49) {
      float c2 = (n + 0.5f)*(197.0f/3136.0f) - 0.5f;
      int r0; float w;
      if (c2 <= 0.f) { r0 = 0; w = 0.f; }
      else if (c2 >= 196.f) { r0 = 196; w = 0.f; }
      else { r0 = (int)c2; w = c2 - (float)r0; }
      int r1 = (r0 < 196) ? r0 + 1 : 196;
      float v0 = AB[(h*197 + r0)*49 + a];
      float v1 = AB[(h*197 + r1)*49 + a];
      val = v0 + w*(v1 - v0);
    }
    ABI[idx2] = val;
  }
}

// ---------------- stage 1 (MFMA): S^T = K·ah^T, exp->P (LDS), O += P·V per wave-owned agents ----
__global__ __launch_bounds__(256) void stage1_mfma(
    const u16* __restrict__ kb, const u16* __restrict__ vb,
    const u16* __restrict__ agentb, const float* __restrict__ PBIT,
    float* __restrict__ pav, float* __restrict__ psum)
{
  int bh = blockIdx.x, chunk = blockIdx.y;
  int b = bh >> 3, h = bh & 7;
  int tid = threadIdx.x, lane = tid & 63, w = tid >> 6;
  int r16 = lane & 15, q4 = lane >> 4;
  __shared__ __align__(16) u16 kld[64*64];   // XOR-swizzled chunks
  __shared__ __align__(16) u16 vt[64*68];    // v transposed [dim][token], stride 68
  __shared__ __align__(16) u16 scb[64*72];   // P [agent][token], stride 72

  int agent = w*16 + r16;
  bf16x8 bah[2];
  {
    const u16* ap = agentb + ((size_t)(b*64 + agent))*512 + h*64 + q4*8;
    bah[0] = *(const bf16x8*)ap;
    bah[1] = *(const bf16x8*)(ap + 32);
  }
  f32x4 Oacc[4];
  #pragma unroll
  for (int nt = 0; nt < 4; nt++) Oacc[nt] = (f32x4){0.f,0.f,0.f,0.f};
  float ssum = 0.f;
  int n0 = chunk * 448;
  const u16* kbase = kb + ((size_t)b*3136)*512 + h*64;
  const u16* vbase = vb + ((size_t)b*3136)*512 + h*64;

  for (int it = 0; it < 7; it++) {
    int nt0 = n0 + it*64;
    __syncthreads();
    #pragma unroll
    for (int i = 0; i < 2; i++) {
      int L = w*128 + i*64 + lane;
      int row = L >> 3, colc = (L & 7) ^ (row & 7);
      async16(kbase + (size_t)(nt0 + row)*512 + colc*8, (char*)kld + (w*128 + i*64)*16);
    }
    uint4 va[2]; int vtok[2], vdc[2];
    #pragma unroll
    for (int i = 0; i < 2; i++) {
      int c = tid + i*256;
      vtok[i] = c >> 3; vdc[i] = (c & 7)*8;
      va[i] = *(const uint4*)(vbase + (size_t)(nt0 + vtok[i])*512 + vdc[i]);
    }
    #pragma unroll
    for (int i = 0; i < 2; i++) {
      u32 uu[4] = {va[i].x, va[i].y, va[i].z, va[i].w};
      #pragma unroll
      for (int e = 0; e < 4; e++) {
        vt[(vdc[i] + 2*e + 0)*68 + vtok[i]] = (u16)(uu[e] & 0xffffu);
        vt[(vdc[i] + 2*e + 1)*68 + vtok[i]] = (u16)(uu[e] >> 16);
      }
    }
    __syncthreads();
    f32x4 S[4];
    #pragma unroll
    for (int mt = 0; mt < 4; mt++) S[mt] = (f32x4){0.f,0.f,0.f,0.f};
    #pragma unroll
    for (int ks = 0; ks < 2; ks++)
      #pragma unroll
      for (int mt = 0; mt < 4; mt++) {
        int row = mt*16 + r16;
        int colc = (ks*4 + q4) ^ (row & 7);
        bf16x8 afr = *(const bf16x8*)&kld[row*64 + colc*8];
        S[mt] = __builtin_amdgcn_mfma_f32_16x16x32_bf16(afr, bah[ks], S[mt], 0,0,0);
      }
    #pragma unroll
    for (int mt = 0; mt < 4; mt++) {
      u64 pk = 0;
      #pragma unroll
      for (int r = 0; r < 4; r++) {
        int tokl = mt*16 + q4*4 + r;
        float bias = PBIT[((size_t)h*3136 + nt0 + tokl)*64 + agent];
        float e = __expf(0.125f*S[mt][r] + bias);
        ssum += e;
        pk |= ((u64)f2bf(e)) << (16*r);
      }
      *(u64*)&scb[agent*72 + mt*16 + q4*4] = pk;
    }
    #pragma unroll
    for (int ks = 0; ks < 2; ks++) {
      bf16x8 ap = *(const bf16x8*)&scb[agent*72 + ks*32 + q4*8];
      #pragma unroll
      for (int nt = 0; nt < 4; nt++) {
        union { bf16x8 v; uint2 u[2]; } bb;
        int dim = nt*16 + r16;
        bb.u[0] = *(const uint2*)&vt[dim*68 + ks*32 + q4*8];
        bb.u[1] = *(const uint2*)&vt[dim*68 + ks*32 + q4*8 + 4];
        Oacc[nt] = __builtin_amdgcn_mfma_f32_16x16x32_bf16(ap, bb.v, Oacc[nt], 0,0,0);
      }
    }
  }
  ssum += __shfl_xor(ssum, 16);
  ssum += __shfl_xor(ssum, 32);
  size_t pb = (size_t)chunk*128 + bh;
  #pragma unroll
  for (int nt = 0; nt < 4; nt++)
    #pragma unroll
    for (int r = 0; r < 4; r++)
      pav[(pb*64 + (w*16 + q4*4 + r))*64 + nt*16 + r16] = Oacc[nt][r];
  if (lane < 16) psum[pb*64 + w*16 + lane] = ssum;
}

// ---------------- reduce partials -> normalized agent_v, transposed bf16 avT[bh][dim][72] ----------
__global__ __launch_bounds__(256) void reduce_agv(
    const float* __restrict__ pav, const float* __restrict__ psum, u16* __restrict__ avTg)
{
  int idx = blockIdx.x*256 + threadIdx.x;   // 128*64*64
  int d = idx & 63, a = (idx >> 6) & 63, bh = idx >> 12;
  float val = 0.f;
  if (a < 49) {
    float acc = 0.f, s = 0.f;
    #pragma unroll
    for (int c = 0; c < 7; c++) {
      acc += pav[(((size_t)c*128 + bh)*64 + a)*64 + d];
      s   += psum[((size_t)c*128 + bh)*64 + a];
    }
    val = acc / s;
  }
  avTg[((size_t)bh*64 + d)*72 + a] = f2bf(val);
}

// ---------------- stage 2 (MFMA): S2 = Q·ah^T, exp->P2 (wave LDS), out = P2·AV ----------------
__global__ __launch_bounds__(256) void stage2_mfma(
    const u16* __restrict__ qb, const u16* __restrict__ agentb,
    const u16* __restrict__ avTg, const float* __restrict__ ABI,
    u16* __restrict__ aout)
{
  int bh = blockIdx.x, chunk = blockIdx.y;
  int b = bh >> 3, h = bh & 7;
  int tid = threadIdx.x, lane = tid & 63, w = tid >> 6;
  int r16 = lane & 15, q4 = lane >> 4;
  __shared__ __align__(16) u16 avs[64*72];
  __shared__ __align__(16) u16 scb2[4*16*72];

  const u16* avsrc = avTg + (size_t)bh*4608;
  #pragma unroll
  for (int rr = 0; rr < 3; rr++) {
    int c = rr*256 + w*64 + lane;
    if (c < 576) async16(avsrc + c*8, (char*)avs + ((size_t)rr*256 + w*64)*16);
  }
  bf16x8 bah[4][2];
  #pragma unroll
  for (int nt = 0; nt < 4; nt++) {
    const u16* ap = agentb + ((size_t)(b*64 + nt*16 + r16))*512 + h*64 + q4*8;
    bah[nt][0] = *(const bf16x8*)ap;
    bah[nt][1] = *(const bf16x8*)(ap + 32);
  }
  __syncthreads();

  u16* scw = scb2 + w*16*72;
  for (int t = 0; t < 7; t++) {
    int tok0 = (chunk*28 + w*7 + t)*16;
    bf16x8 aq[2];
    {
      const u16* qp = qb + ((size_t)b*3136 + tok0 + r16)*512 + h*64 + q4*8;
      aq[0] = *(const bf16x8*)qp;
      aq[1] = *(const bf16x8*)(qp + 32);
    }
    f32x4 S[4];
    #pragma unroll
    for (int nt = 0; nt < 4; nt++) S[nt] = (f32x4){0.f,0.f,0.f,0.f};
    #pragma unroll
    for (int ks = 0; ks < 2; ks++)
      #pragma unroll
      for (int nt = 0; nt < 4; nt++)
        S[nt] = __builtin_amdgcn_mfma_f32_16x16x32_bf16(aq[ks], bah[nt][ks], S[nt], 0,0,0);
    float rs[4] = {0.f,0.f,0.f,0.f};
    #pragma unroll
    for (int nt = 0; nt < 4; nt++)
      #pragma unroll
      for (int r = 0; r < 4; r++) {
        int tokl = q4*4 + r;
        float bias = ABI[((size_t)h*3136 + tok0 + tokl)*64 + nt*16 + r16];
        float e = __expf(0.125f*S[nt][r] + bias);
        rs[r] += e;
        scw[tokl*72 + nt*16 + r16] = f2bf(e);
      }
    #pragma unroll
    for (int m = 1; m <= 8; m <<= 1)
      #pragma unroll
      for (int r = 0; r < 4; r++) rs[r] += __shfl_xor(rs[r], m);
    f32x4 O[4];
    #pragma unroll
    for (int nt = 0; nt < 4; nt++) O[nt] = (f32x4){0.f,0.f,0.f,0.f};
    #pragma unroll
    for (int ks = 0; ks < 2; ks++) {
      bf16x8 ap2 = *(const bf16x8*)&scw[r16*72 + ks*32 + q4*8];
      #pragma unroll
      for (int nt = 0; nt < 4; nt++) {
        bf16x8 bv = *(const bf16x8*)&avs[(nt*16 + r16)*72 + ks*32 + q4*8];
        O[nt] = __builtin_amdgcn_mfma_f32_16x16x32_bf16(ap2, bv, O[nt], 0,0,0);
      }
    }
    float inv[4];
    #pragma unroll
    for (int r = 0; r < 4; r++) inv[r] = 1.0f / rs[r];
    #pragma unroll
    for (int nt = 0; nt < 4; nt++)
      #pragma unroll
      for (int r = 0; r < 4; r++)
        aout[((size_t)b*3136 + tok0 + q4*4 + r)*512 + h*64 + nt*16 + r16] = f2bf(O[nt][r]*inv[r]);
  }
}

// ---------------- depthwise 3x3 + residual: wave = token run, lane = 8-channel group ----------------
__global__ __launch_bounds__(256) void dwc_add2(
    const u16* __restrict__ vb, const float* __restrict__ w_dwc,
    const float* __restrict__ b_dwc, u16* __restrict__ io)
{
  int wave = (blockIdx.x << 2) + (threadIdx.x >> 6);   // 3136 waves, 16 tokens each
  int lane = threadIdx.x & 63;
  int c0 = lane * 8;

  float wt[9][8];
  {
    float tmp[72];
    const float4* wp = (const float4*)(w_dwc + c0*9);
    #pragma unroll
    for (int i = 0; i < 18; i++) {
      float4 v4 = wp[i];
      tmp[4*i] = v4.x; tmp[4*i+1] = v4.y; tmp[4*i+2] = v4.z; tmp[4*i+3] = v4.w;
    }
    #pragma unroll
    for (int j = 0; j < 8; j++)
      #pragma unroll
      for (int tp = 0; tp < 9; tp++) wt[tp][j] = tmp[j*9 + tp];
  }
  float bias[8];
  {
    const float4* bp = (const float4*)(b_dwc + c0);
    float4 a4 = bp[0], b4 = bp[1];
    bias[0]=a4.x; bias[1]=a4.y; bias[2]=a4.z; bias[3]=a4.w;
    bias[4]=b4.x; bias[5]=b4.y; bias[6]=b4.z; bias[7]=b4.w;
  }

  int t0 = wave * 16;
  int b = t0 / 3136;
  int n0 = t0 - b*3136;
  const u16* vbase = vb + ((size_t)b*3136)*512 + c0;

  for (int ti = 0; ti < 16; ti++) {
    int n = n0 + ti;
    int y = n / 56, x = n - y*56;
    size_t toff = ((size_t)b*3136 + n)*512 + c0;
    float acc[8];
    {
      uint4 uo = *(const uint4*)(io + toff);
      u32 uu[4] = {uo.x, uo.y, uo.z, uo.w};
      #pragma unroll
      for (int e = 0; e < 4; e++) {
        acc[2*e+0] = bflo(uu[e]) + bias[2*e+0];
        acc[2*e+1] = bfhi(uu[e]) + bias[2*e+1];
      }
    }
    #pragma unroll
    for (int dy = 0; dy < 3; dy++) {
      int yy = y + dy - 1;
      if (yy < 0 || yy > 55) continue;
      #pragma unroll
      for (int dx = 0; dx < 3; dx++) {
        int xx = x + dx - 1;
        if (xx < 0 || xx > 55) continue;
        uint4 uv = *(const uint4*)(vbase + ((size_t)(yy*56 + xx) << 9));
        u32 uu[4] = {uv.x, uv.y, uv.z, uv.w};
        const float* wr = wt[dy*3 + dx];
        #pragma unroll
        for (int e = 0; e < 4; e++) {
          acc[2*e+0] += bflo(uu[e]) * wr[2*e+0];
          acc[2*e+1] += bfhi(uu[e]) * wr[2*e+1];
        }
      }
    }
    uint4 pk;
    pk.x = (u32)f2bf(acc[0]) | ((u32)f2bf(acc[1]) << 16);
    pk.y = (u32)f2bf(acc[2]) | ((u32)f2bf(acc[3]) << 16);
    pk.z = (u32)f2bf(acc[4]) | ((u32)f2bf(acc[5]) << 16);
    pk.w = (u32)f2bf(acc[6]) | ((u32)f2bf(acc[7]) << 16);
    *(uint4*)(io + toff) = pk;
  }
}

extern "C" void kernel_launch(void* const* d_in, const int* in_sizes, int n_in,
                              void* d_out, int out_size, void* d_ws, size_t ws_size,
                              hipStream_t stream)
{
  const float* x       = (const float*)d_in[0];
  const float* w_qkv   = (const float*)d_in[1];
  const float* w_proj  = (const float*)d_in[2];
  const float* b_proj  = (const float*)d_in[3];
  const float* w_dwc   = (const float*)d_in[4];
  const float* b_dwc   = (const float*)d_in[5];
  const float* an_bias = (const float*)d_in[6];
  const float* na_bias = (const float*)d_in[7];
  const float* ah_bias = (const float*)d_in[8];
  const float* aw_bias = (const float*)d_in[9];
  const float* ha_bias = (const float*)d_in[10];
  const float* wa_bias = (const float*)d_in[11];
  const float* ca_bias = (const float*)d_in[12];

  if (ws_size < 210000000u) return;

  char* p = (char*)d_ws;
  u16* regA   = (u16*)p;  p += 51380224;   // xb -> {PBIT,ABI,pav,psum,avTg}
  u16* qb     = (u16*)p;  p += 51380224;
  u16* kb     = (u16*)p;  p += 51380224;   // k -> attn_out (aout) after stage1
  u16* vb     = (u16*)p;  p += 51380224;
  u16* wqkvb  = (u16*)p;  p += 1572864;
  u16* wprojb = (u16*)p;  p += 524288;
  u16* agentb = (u16*)p;  p += 1048576;    // 16 x 64(padded) x 512 bf16
  float* PB   = (float*)p; p += 307456;
  float* AB   = (float*)p; p += 309248;

  float* PBIT = (float*)((char*)regA);                  // 6,422,528
  float* ABI  = (float*)((char*)regA + 6422528);        // 6,422,528
  float* pav  = (float*)((char*)regA + 12845056);       // 14,680,064
  float* psum = (float*)((char*)regA + 27525120);       //    229,376
  u16*   avTg = (u16*)  ((char*)regA + 27754496);       //  1,179,648
  u16*   aout = kb;

  cast_bf16<<<25088, 256, 0, stream>>>(x, regA, 6422528);
  cast_bf16<<<768,   256, 0, stream>>>(w_qkv, wqkvb, 196608);
  cast_bf16<<<256,   256, 0, stream>>>(w_proj, wprojb, 65536);

  gemm256<<<dim3(196,6), 512, 0, stream>>>(regA, wqkvb, 512, 0, qb, kb, vb, nullptr, nullptr);
  pool_q<<<2048, 256, 0, stream>>>(qb, agentb);
  bias_pre<<<602, 256, 0, stream>>>(an_bias, na_bias, ah_bias, aw_bias, ha_bias, wa_bias, ca_bias, PB, AB);
  bias_expand2<<<12544, 256, 0, stream>>>(PB, AB, PBIT, ABI);
  stage1_mfma<<<dim3(128,7), 256, 0, stream>>>(kb, vb, agentb, PBIT, pav, psum);
  reduce_agv<<<2048, 256, 0, stream>>>(pav, psum, avTg);
  stage2_mfma<<<dim3(128,7), 256, 0, stream>>>(qb, agentb, avTg, ABI, aout);
  dwc_add2<<<784, 256, 0, stream>>>(vb, w_dwc, b_dwc, aout);
  gemm256<<<dim3(196,2), 512, 0, stream>>>(aout, wprojb, 512, 1, nullptr, nullptr, nullptr,
                                           (float*)d_out, b_proj);
}

// Round 2
// 526.314 us; speedup vs baseline: 1.0455x; 1.0063x over previous
//
#include <hip/hip_runtime.h>

typedef unsigned short u16;
typedef unsigned int   u32;
typedef unsigned long long u64;
typedef float  f32x4  __attribute__((ext_vector_type(4)));
typedef __bf16 bf16x8 __attribute__((ext_vector_type(8)));

#define DEV static __device__ __forceinline__

DEV float bf2f(u16 u){ union{float f;u32 i;}v; v.i=((u32)u)<<16; return v.f; }
DEV float bflo(u32 u){ union{float f;u32 i;}v; v.i=u<<16; return v.f; }
DEV float bfhi(u32 u){ union{float f;u32 i;}v; v.i=u&0xffff0000u; return v.f; }
DEV u16   f2bf(float f){ union{float f;u32 i;}v; v.f=f; return (u16)((v.i + 0x7fffu + ((v.i>>16)&1u))>>16); }

DEV void async16(const void* g, void* l){
  __builtin_amdgcn_global_load_lds((const __attribute__((address_space(1))) void*)g,
                                   (__attribute__((address_space(3))) void*)l, 16, 0, 0);
}

// ---------------- cast fp32 -> bf16 (4 elems/thread) ----------------
__global__ __launch_bounds__(256) void cast_bf16(const float* __restrict__ in,
                                                 u16* __restrict__ out, int n4)
{
  int i = blockIdx.x*256 + threadIdx.x;
  if (i >= n4) return;
  float4 v = ((const float4*)in)[i];
  ushort4 o;
  o.x = f2bf(v.x); o.y = f2bf(v.y); o.z = f2bf(v.z); o.w = f2bf(v.w);
  ((ushort4*)out)[i] = o;
}

// ---------------- bf16 MFMA GEMM, 256x256 tile, 3-region counted-vmcnt schedule ----------------
// C[m][n] = sum_k A[m][k]*W[n][k].  512 threads = 8 waves (2M x 4N), 128x64 C per wave.
// BK=64, double-buffered 128KiB LDS, source-side XOR chunk swizzle (0 bank conflicts),
// counted vmcnt(6) once per K-tile, setprio around MFMA clusters.
// Block remap: y-fastest logical order + XCD-chunked so the ny blocks sharing an A-panel
// run concurrently on ONE XCD -> A-panel served from that XCD's L2 (was ~3x L3/HBM refetch).
//
// Staging safety ledger (per K-tile T, reading buf[T&1]):
//   R1: reads A frags mi0-3 + ALL B frags; stages (T+1,B-h1) -> buf[T^1] (disjoint); 32 MFMA.
//       (merged old ph0+ph1: the removed barrier only separated two register-only MFMA runs)
//   R2: reads A frags mi4-7; stages (T+2,B-h0) -> Bs buf[T&1] (all B reads drained by R1's
//       post-lgkm barrier); 16 MFMA; post-barrier certifies all waves' A reads drained.
//   R3: stages (T+2,A-h0),(T+2,A-h1) -> As buf[T&1] (A reads drained per R2); 16 MFMA;
//       vmcnt(6) = exactly the 3 stages of R2+R3 in flight; tile T+1 fully landed.
__global__ __launch_bounds__(512, 2) void gemm256(
    const u16* __restrict__ A, const u16* __restrict__ W, int K, int mode,
    u16* __restrict__ oq, u16* __restrict__ okk, u16* __restrict__ ov,
    float* __restrict__ of, const float* __restrict__ bias)
{
  __shared__ __align__(16) u16 As[2*16384];   // 2 bufs x 256 rows x 64 (swizzled 16B chunks)
  __shared__ __align__(16) u16 Bs[2*16384];
  const int tid  = threadIdx.x;
  const int w = tid >> 6, lane = tid & 63;
  const int wm = w >> 2, wn = w & 3;          // 2 M-waves x 4 N-waves
  const int r16 = lane & 15, q4 = lane >> 4;
  const int xr = r16 & 7;

  // panel-grouped XCD-chunked block remap (bijective: nwg % 8 == 0 for both launches)
  const int ny  = gridDim.y;                  // 6 (qkv) or 2 (proj)
  const int nwg = (int)gridDim.x * ny;        // 1176 or 392
  const int cpx = nwg >> 3;
  const int hw  = blockIdx.x + gridDim.x*blockIdx.y;
  const int lb  = (hw & 7)*cpx + (hw >> 3);
  const int tx  = lb / ny;                    // A row-panel index (0..195)
  const int ty  = lb - tx*ny;                 // B col-tile index (0..ny-1)

  const size_t Abase = (size_t)tx * 256 * K;
  const size_t Bbase = (size_t)ty * 256 * K;
  const int NT = K >> 6;

// one half-tile = 128 rows x 64 cols bf16 = 16KB = 512 thr x 2 x 16B
#define STAGE(t, half, arr) do { \
    const u16* _src = (arr) ? (W + Bbase) : (A + Abase); \
    u16* _dst = ((arr) ? Bs : As) + (((t) & 1) * 16384 + (half) * 8192); \
    const int _k0 = (t) << 6; \
    _Pragma("unroll") \
    for (int _i = 0; _i < 2; _i++) { \
      int _s = _i*512 + tid; \
      int _row = _s >> 3; \
      int _c = (_s & 7) ^ (_row & 7); \
      async16(_src + (size_t)((half)*128 + _row) * K + _k0 + _c*8, (char*)_dst + (size_t)_s * 16); \
    } \
  } while(0)

#define READ_A(MI0) do { \
    _Pragma("unroll") \
    for (int _i = 0; _i < 4; _i++) { \
      int _row = wm*128 + ((MI0)+_i)*16 + r16; \
      _Pragma("unroll") \
      for (int _ks = 0; _ks < 2; _ks++) \
        af[_i][_ks] = *(const bf16x8*)&As[boff + _row*64 + (((_ks*4 + q4) ^ xr) * 8)]; \
    } \
  } while(0)

#define READ_B() do { \
    _Pragma("unroll") \
    for (int _j = 0; _j < 4; _j++) { \
      int _row = wn*64 + _j*16 + r16; \
      _Pragma("unroll") \
      for (int _ks = 0; _ks < 2; _ks++) \
        bfr[_j][_ks] = *(const bf16x8*)&Bs[boff + _row*64 + (((_ks*4 + q4) ^ xr) * 8)]; \
    } \
  } while(0)

#define MFMA_Q(MI0, NI0) do { \
    _Pragma("unroll") \
    for (int _ks = 0; _ks < 2; _ks++) \
      _Pragma("unroll") \
      for (int _i = 0; _i < 4; _i++) \
        _Pragma("unroll") \
        for (int _j = 0; _j < 2; _j++) \
          acc[(MI0)+_i][(NI0)+_j] = __builtin_amdgcn_mfma_f32_16x16x32_bf16( \
              bfr[(NI0)+_j][_ks], af[_i][_ks], acc[(MI0)+_i][(NI0)+_j], 0,0,0); \
  } while(0)

  f32x4 acc[8][4];
  #pragma unroll
  for (int i=0;i<8;i++)
    #pragma unroll
    for (int j=0;j<4;j++) acc[i][j] = (f32x4){0.f,0.f,0.f,0.f};
  bf16x8 af[4][2], bfr[4][2];

  // ---- prologue: tile0 fully, tile1 {B-h0, A-h0, A-h1}; vmcnt(6) -> tile0 landed ----
  STAGE(0,0,0); STAGE(0,1,0); STAGE(0,0,1); STAGE(0,1,1);
  STAGE(1,0,1); STAGE(1,0,0); STAGE(1,1,0);
  asm volatile("s_waitcnt vmcnt(6)" ::: "memory");
  __builtin_amdgcn_s_barrier();

  for (int T = 0; T < NT; ++T) {
    const int boff = (T & 1) * 16384;
    // ---- R1: A(0..3) + all B reads; stage (T+1,B-h1); 32 MFMA ----
    READ_A(0);
    READ_B();
    if (T+1 < NT) STAGE(T+1, 1, 1);
    __builtin_amdgcn_s_barrier();
    asm volatile("s_waitcnt lgkmcnt(0)" ::: "memory");
    __builtin_amdgcn_sched_barrier(0);
    __builtin_amdgcn_s_setprio(1);
    MFMA_Q(0, 0);
    MFMA_Q(0, 2);
    __builtin_amdgcn_s_setprio(0);
    __builtin_amdgcn_s_barrier();
    // ---- R2: A(4..7) reads; stage (T+2,B-h0); 16 MFMA ----
    READ_A(4);
    if (T+2 < NT) STAGE(T+2, 0, 1);
    __builtin_amdgcn_s_barrier();
    asm volatile("s_waitcnt lgkmcnt(0)" ::: "memory");
    __builtin_amdgcn_sched_barrier(0);
    __builtin_amdgcn_s_setprio(1);
    MFMA_Q(4, 0);
    __builtin_amdgcn_s_setprio(0);
    __builtin_amdgcn_s_barrier();          // certifies all waves' A reads complete
    // ---- R3: stage (T+2,A-h0/h1); 16 MFMA; counted vmcnt ----
    if (T+2 < NT) { STAGE(T+2, 0, 0); STAGE(T+2, 1, 0); }
    __builtin_amdgcn_s_setprio(1);
    MFMA_Q(4, 2);
    __builtin_amdgcn_s_setprio(0);
    if (T+2 < NT)      asm volatile("s_waitcnt vmcnt(6)" ::: "memory");
    else if (T+1 < NT) asm volatile("s_waitcnt vmcnt(0)" ::: "memory");
    __builtin_amdgcn_s_barrier();
  }

#undef STAGE
#undef READ_A
#undef READ_B
#undef MFMA_Q

  // ---- epilogue: same fragment->C mapping as verified kernel ----
  const int m0  = tx*256 + wm*128;
  const int n0g = ty*256 + wn*64;
  if (mode == 0){
    int sel = ty >> 1;                       // 256-n tiles never straddle q/k/v
    u16* dst = sel==0 ? oq : (sel==1 ? okk : ov);
    #pragma unroll
    for (int i=0;i<8;i++){
      int token = m0 + i*16 + r16;
      #pragma unroll
      for (int j=0;j<4;j++){
        int col = (n0g + j*16 + q4*4) & 511;
        uint2 pk;
        pk.x = (u32)f2bf(acc[i][j][0]) | ((u32)f2bf(acc[i][j][1]) << 16);
        pk.y = (u32)f2bf(acc[i][j][2]) | ((u32)f2bf(acc[i][j][3]) << 16);
        *(uint2*)&dst[(size_t)token*512 + col] = pk;
      }
    }
  } else {
    #pragma unroll
    for (int j=0;j<4;j++){
      int nbase = n0g + j*16 + q4*4;
      float4 b4 = *(const float4*)&bias[nbase];
      #pragma unroll
      for (int i=0;i<8;i++){
        int token = m0 + i*16 + r16;
        float4 o4 = { acc[i][j][0]+b4.x, acc[i][j][1]+b4.y,
                      acc[i][j][2]+b4.z, acc[i][j][3]+b4.w };
        *(float4*)&of[(size_t)token*512 + nbase] = o4;
      }
    }
  }
}

// ---------------- agent pooling: exact 8x8 block mean of q, uint4-vectorized ----------------
// thread = (b, agent-slot, 8-channel group); per-channel summation order identical to the
// scalar version (iy outer, ix inner) -> bit-identical output.
__global__ __launch_bounds__(256) void pool_q(const u16* __restrict__ qb, u16* __restrict__ agentb)
{
  int idx = blockIdx.x*256 + threadIdx.x;          // 16*64*64
  int c8 = idx & 63;
  int ba = idx >> 6;
  int a = ba & 63, b = ba >> 6;
  u16* dst = agentb + ((size_t)(b*64 + a))*512 + c8*8;
  if (a >= 49) { *(uint4*)dst = (uint4){0,0,0,0}; return; }
  int ay = a / 7, ax = a % 7;
  const u16* base = qb + ((size_t)b*3136 + (size_t)(ay*8)*56 + ax*8)*512 + c8*8;
  float acc[8] = {0.f,0.f,0.f,0.f,0.f,0.f,0.f,0.f};
  #pragma unroll
  for (int iy=0; iy<8; iy++){
    #pragma unroll
    for (int ix=0; ix<8; ix++){
      uint4 uv = *(const uint4*)(base + ((size_t)(iy*56 + ix) << 9));
      u32 uu[4] = {uv.x, uv.y, uv.z, uv.w};
      #pragma unroll
      for (int e=0;e<4;e++){ acc[2*e+0] += bflo(uu[e]); acc[2*e+1] += bfhi(uu[e]); }
    }
  }
  uint4 pk;
  pk.x = (u32)f2bf(acc[0]*0.015625f) | ((u32)f2bf(acc[1]*0.015625f) << 16);
  pk.y = (u32)f2bf(acc[2]*0.015625f) | ((u32)f2bf(acc[3]*0.015625f) << 16);
  pk.z = (u32)f2bf(acc[4]*0.015625f) | ((u32)f2bf(acc[5]*0.015625f) << 16);
  pk.w = (u32)f2bf(acc[6]*0.015625f) | ((u32)f2bf(acc[7]*0.015625f) << 16);
  *(uint4*)dst = pk;
}

// ---------------- bias tables: PB[8][49][196], AB[8][197][49] ----------------
DEV void lin1(float c, int S, int& i0, int& i1, float& w){
  if (c <= 0.f){ i0=0; i1=0; w=0.f; }
  else if (c >= (float)(S-1)){ i0=S-1; i1=S-1; w=0.f; }
  else { i0=(int)c; i1=i0+1; w=c-(float)i0; }
}
DEV float bilin7(const float* s, int Y, int X){
  int y0,y1,x0,x1; float wy,wx;
  lin1(0.5f*Y - 0.25f, 7, y0,y1,wy);
  lin1(0.5f*X - 0.25f, 7, x0,x1,wx);
  float v0 = s[y0*7+x0] + wx*(s[y0*7+x1]-s[y0*7+x0]);
  float v1 = s[y1*7+x0] + wx*(s[y1*7+x1]-s[y1*7+x0]);
  return v0 + wy*(v1 - v0);
}
__global__ __launch_bounds__(256) void bias_pre(
    const float* __restrict__ an_bias, const float* __restrict__ na_bias,
    const float* __restrict__ ah_bias, const float* __restrict__ aw_bias,
    const float* __restrict__ ha_bias, const float* __restrict__ wa_bias,
    const float* __restrict__ ca_bias, float* __restrict__ PB, float* __restrict__ AB)
{
  int idx = blockIdx.x*256 + threadIdx.x;
  if (idx < 8*49*196){
    int j = idx % 196; int ha = idx / 196; int a = ha % 49, h = ha / 49;
    int wy = j / 14, wx = j % 14;
    PB[idx] = bilin7(an_bias + (h*49+a)*49, wy, wx)
            + ah_bias[(h*49+a)*14 + wy] + aw_bias[(h*49+a)*14 + wx];
  }
  int idx2 = idx - 8*49*196;
  if (idx2 >= 0 && idx2 < 8*197*49){
    int a = idx2 % 49; int hr = idx2 / 49; int r = hr % 197, h = hr / 197;
    float v;
    if (r == 0) v = ca_bias[h*49 + a];
    else {
      int j = r - 1; int wy = j / 14, wx = j % 14;
      v = bilin7(na_bias + (h*49+a)*49, wy, wx)
        + ha_bias[(h*14+wy)*49 + a] + wa_bias[(h*14+wx)*49 + a];
    }
    AB[idx2] = v;
  }
}

// ---------------- merged bias expand: PBIT[h][n][64] and ABI[h][n][64] ----------------
__global__ __launch_bounds__(256) void bias_expand2(
    const float* __restrict__ PB, const float* __restrict__ AB,
    float* __restrict__ PBIT, float* __restrict__ ABI)
{
  int idx = blockIdx.x*256 + threadIdx.x;
  if (idx < 1605632) {
    int a = idx & 63; int t = idx >> 6; int n = t % 3136; int h = t / 3136;
    float val = -1e30f;
    if (a < 49) {
      const float* row = PB + (h*49 + a)*196;
      float c1 = (n + 0.5f)*0.0625f - 0.5f;
      if (c1 <= 0.f) val = row[0];
      else if (c1 >= 195.f) val = row[195];
      else { int j0 = (int)c1; float w = c1 - (float)j0; val = row[j0] + w*(row[j0+1]-row[j0]); }
    }
    PBIT[idx] = val;
  } else {
    int idx2 = idx - 1605632;
    if (idx2 >= 1605632) return;
    int a = idx2 & 63; int t = idx2 >> 6; int n = t % 3136; int h = t / 3136;
    float val = -1e30f;
    if (a < 49) {
      float c2 = (n + 0.5f)*(197.0f/3136.0f) - 0.5f;
      int r0; float w;
      if (c2 <= 0.f) { r0 = 0; w = 0.f; }
      else if (c2 >= 196.f) { r0 = 196; w = 0.f; }
      else { r0 = (int)c2; w = c2 - (float)r0; }
      int r1 = (r0 < 196) ? r0 + 1 : 196;
      float v0 = AB[(h*197 + r0)*49 + a];
      float v1 = AB[(h*197 + r1)*49 + a];
      val = v0 + w*(v1 - v0);
    }
    ABI[idx2] = val;
  }
}

// ---------------- stage 1 (MFMA): S^T = K·ah^T, exp->P (LDS), O += P·V per wave-owned agents ----
__global__ __launch_bounds__(256) void stage1_mfma(
    const u16* __restrict__ kb, const u16* __restrict__ vb,
    const u16* __restrict__ agentb, const float* __restrict__ PBIT,
    float* __restrict__ pav, float* __restrict__ psum)
{
  int bh = blockIdx.x, chunk = blockIdx.y;
  int b = bh >> 3, h = bh & 7;
  int tid = threadIdx.x, lane = tid & 63, w = tid >> 6;
  int r16 = lane & 15, q4 = lane >> 4;
  __shared__ __align__(16) u16 kld[64*64];   // XOR-swizzled chunks
  __shared__ __align__(16) u16 vt[64*68];    // v transposed [dim][token], stride 68
  __shared__ __align__(16) u16 scb[64*72];   // P [agent][token], stride 72

  int agent = w*16 + r16;
  bf16x8 bah[2];
  {
    const u16* ap = agentb + ((size_t)(b*64 + agent))*512 + h*64 + q4*8;
    bah[0] = *(const bf16x8*)ap;
    bah[1] = *(const bf16x8*)(ap + 32);
  }
  f32x4 Oacc[4];
  #pragma unroll
  for (int nt = 0; nt < 4; nt++) Oacc[nt] = (f32x4){0.f,0.f,0.f,0.f};
  float ssum = 0.f;
  int n0 = chunk * 448;
  const u16* kbase = kb + ((size_t)b*3136)*512 + h*64;
  const u16* vbase = vb + ((size_t)b*3136)*512 + h*64;

  for (int it = 0; it < 7; it++) {
    int nt0 = n0 + it*64;
    __syncthreads();
    #pragma unroll
    for (int i = 0; i < 2; i++) {
      int L = w*128 + i*64 + lane;
      int row = L >> 3, colc = (L & 7) ^ (row & 7);
      async16(kbase + (size_t)(nt0 + row)*512 + colc*8, (char*)kld + (w*128 + i*64)*16);
    }
    uint4 va[2]; int vtok[2], vdc[2];
    #pragma unroll
    for (int i = 0; i < 2; i++) {
      int c = tid + i*256;
      vtok[i] = c >> 3; vdc[i] = (c & 7)*8;
      va[i] = *(const uint4*)(vbase + (size_t)(nt0 + vtok[i])*512 + vdc[i]);
    }
    #pragma unroll
    for (int i = 0; i < 2; i++) {
      u32 uu[4] = {va[i].x, va[i].y, va[i].z, va[i].w};
      #pragma unroll
      for (int e = 0; e < 4; e++) {
        vt[(vdc[i] + 2*e + 0)*68 + vtok[i]] = (u16)(uu[e] & 0xffffu);
        vt[(vdc[i] + 2*e + 1)*68 + vtok[i]] = (u16)(uu[e] >> 16);
      }
    }
    __syncthreads();
    f32x4 S[4];
    #pragma unroll
    for (int mt = 0; mt < 4; mt++) S[mt] = (f32x4){0.f,0.f,0.f,0.f};
    #pragma unroll
    for (int ks = 0; ks < 2; ks++)
      #pragma unroll
      for (int mt = 0; mt < 4; mt++) {
        int row = mt*16 + r16;
        int colc = (ks*4 + q4) ^ (row & 7);
        bf16x8 afr = *(const bf16x8*)&kld[row*64 + colc*8];
        S[mt] = __builtin_amdgcn_mfma_f32_16x16x32_bf16(afr, bah[ks], S[mt], 0,0,0);
      }
    #pragma unroll
    for (int mt = 0; mt < 4; mt++) {
      u64 pk = 0;
      #pragma unroll
      for (int r = 0; r < 4; r++) {
        int tokl = mt*16 + q4*4 + r;
        float bias = PBIT[((size_t)h*3136 + nt0 + tokl)*64 + agent];
        float e = __expf(0.125f*S[mt][r] + bias);
        ssum += e;
        pk |= ((u64)f2bf(e)) << (16*r);
      }
      *(u64*)&scb[agent*72 + mt*16 + q4*4] = pk;
    }
    #pragma unroll
    for (int ks = 0; ks < 2; ks++) {
      bf16x8 ap = *(const bf16x8*)&scb[agent*72 + ks*32 + q4*8];
      #pragma unroll
      for (int nt = 0; nt < 4; nt++) {
        union { bf16x8 v; uint2 u[2]; } bb;
        int dim = nt*16 + r16;
        bb.u[0] = *(const uint2*)&vt[dim*68 + ks*32 + q4*8];
        bb.u[1] = *(const uint2*)&vt[dim*68 + ks*32 + q4*8 + 4];
        Oacc[nt] = __builtin_amdgcn_mfma_f32_16x16x32_bf16(ap, bb.v, Oacc[nt], 0,0,0);
      }
    }
  }
  ssum += __shfl_xor(ssum, 16);
  ssum += __shfl_xor(ssum, 32);
  size_t pb = (size_t)chunk*128 + bh;
  #pragma unroll
  for (int nt = 0; nt < 4; nt++)
    #pragma unroll
    for (int r = 0; r < 4; r++)
      pav[(pb*64 + (w*16 + q4*4 + r))*64 + nt*16 + r16] = Oacc[nt][r];
  if (lane < 16) psum[pb*64 + w*16 + lane] = ssum;
}

// ---------------- reduce partials -> normalized agent_v, transposed bf16 avT[bh][dim][72] ----------
__global__ __launch_bounds__(256) void reduce_agv(
    const float* __restrict__ pav, const float* __restrict__ psum, u16* __restrict__ avTg)
{
  int idx = blockIdx.x*256 + threadIdx.x;   // 128*64*64
  int d = idx & 63, a = (idx >> 6) & 63, bh = idx >> 12;
  float val = 0.f;
  if (a < 49) {
    float acc = 0.f, s = 0.f;
    #pragma unroll
    for (int c = 0; c < 7; c++) {
      acc += pav[(((size_t)c*128 + bh)*64 + a)*64 + d];
      s   += psum[((size_t)c*128 + bh)*64 + a];
    }
    val = acc / s;
  }
  avTg[((size_t)bh*64 + d)*72 + a] = f2bf(val);
}

// ---------------- stage 2 (MFMA): S2 = Q·ah^T, exp->P2 (wave LDS), out = P2·AV ----------------
__global__ __launch_bounds__(256) void stage2_mfma(
    const u16* __restrict__ qb, const u16* __restrict__ agentb,
    const u16* __restrict__ avTg, const float* __restrict__ ABI,
    u16* __restrict__ aout)
{
  int bh = blockIdx.x, chunk = blockIdx.y;
  int b = bh >> 3, h = bh & 7;
  int tid = threadIdx.x, lane = tid & 63, w = tid >> 6;
  int r16 = lane & 15, q4 = lane >> 4;
  __shared__ __align__(16) u16 avs[64*72];
  __shared__ __align__(16) u16 scb2[4*16*72];

  const u16* avsrc = avTg + (size_t)bh*4608;
  #pragma unroll
  for (int rr = 0; rr < 3; rr++) {
    int c = rr*256 + w*64 + lane;
    if (c < 576) async16(avsrc + c*8, (char*)avs + ((size_t)rr*256 + w*64)*16);
  }
  bf16x8 bah[4][2];
  #pragma unroll
  for (int nt = 0; nt < 4; nt++) {
    const u16* ap = agentb + ((size_t)(b*64 + nt*16 + r16))*512 + h*64 + q4*8;
    bah[nt][0] = *(const bf16x8*)ap;
    bah[nt][1] = *(const bf16x8*)(ap + 32);
  }
  __syncthreads();

  u16* scw = scb2 + w*16*72;
  for (int t = 0; t < 7; t++) {
    int tok0 = (chunk*28 + w*7 + t)*16;
    bf16x8 aq[2];
    {
      const u16* qp = qb + ((size_t)b*3136 + tok0 + r16)*512 + h*64 + q4*8;
      aq[0] = *(const bf16x8*)qp;
      aq[1] = *(const bf16x8*)(qp + 32);
    }
    f32x4 S[4];
    #pragma unroll
    for (int nt = 0; nt < 4; nt++) S[nt] = (f32x4){0.f,0.f,0.f,0.f};
    #pragma unroll
    for (int ks = 0; ks < 2; ks++)
      #pragma unroll
      for (int nt = 0; nt < 4; nt++)
        S[nt] = __builtin_amdgcn_mfma_f32_16x16x32_bf16(aq[ks], bah[nt][ks], S[nt], 0,0,0);
    float rs[4] = {0.f,0.f,0.f,0.f};
    #pragma unroll
    for (int nt = 0; nt < 4; nt++)
      #pragma unroll
      for (int r = 0; r < 4; r++) {
        int tokl = q4*4 + r;
        float bias = ABI[((size_t)h*3136 + tok0 + tokl)*64 + nt*16 + r16];
        float e = __expf(0.125f*S[nt][r] + bias);
        rs[r] += e;
        scw[tokl*72 + nt*16 + r16] = f2bf(e);
      }
    #pragma unroll
    for (int m = 1; m <= 8; m <<= 1)
      #pragma unroll
      for (int r = 0; r < 4; r++) rs[r] += __shfl_xor(rs[r], m);
    f32x4 O[4];
    #pragma unroll
    for (int nt = 0; nt < 4; nt++) O[nt] = (f32x4){0.f,0.f,0.f,0.f};
    #pragma unroll
    for (int ks = 0; ks < 2; ks++) {
      bf16x8 ap2 = *(const bf16x8*)&scw[r16*72 + ks*32 + q4*8];
      #pragma unroll
      for (int nt = 0; nt < 4; nt++) {
        bf16x8 bv = *(const bf16x8*)&avs[(nt*16 + r16)*72 + ks*32 + q4*8];
        O[nt] = __builtin_amdgcn_mfma_f32_16x16x32_bf16(ap2, bv, O[nt], 0,0,0);
      }
    }
    float inv[4];
    #pragma unroll
    for (int r = 0; r < 4; r++) inv[r] = 1.0f / rs[r];
    #pragma unroll
    for (int nt = 0; nt < 4; nt++)
      #pragma unroll
      for (int r = 0; r < 4; r++)
        aout[((size_t)b*3136 + tok0 + q4*4 + r)*512 + h*64 + nt*16 + r16] = f2bf(O[nt][r]*inv[r]);
  }
}

// ---------------- depthwise 3x3 + residual: wave = token run, lane = 8-channel group ----------------
__global__ __launch_bounds__(256) void dwc_add2(
    const u16* __restrict__ vb, const float* __restrict__ w_dwc,
    const float* __restrict__ b_dwc, u16* __restrict__ io)
{
  int wave = (blockIdx.x << 2) + (threadIdx.x >> 6);   // 3136 waves, 16 tokens each
  int lane = threadIdx.x & 63;
  int c0 = lane * 8;

  float wt[9][8];
  {
    float tmp[72];
    const float4* wp = (const float4*)(w_dwc + c0*9);
    #pragma unroll
    for (int i = 0; i < 18; i++) {
      float4 v4 = wp[i];
      tmp[4*i] = v4.x; tmp[4*i+1] = v4.y; tmp[4*i+2] = v4.z; tmp[4*i+3] = v4.w;
    }
    #pragma unroll
    for (int j = 0; j < 8; j++)
      #pragma unroll
      for (int tp = 0; tp < 9; tp++) wt[tp][j] = tmp[j*9 + tp];
  }
  float bias[8];
  {
    const float4* bp = (const float4*)(b_dwc + c0);
    float4 a4 = bp[0], b4 = bp[1];
    bias[0]=a4.x; bias[1]=a4.y; bias[2]=a4.z; bias[3]=a4.w;
    bias[4]=b4.x; bias[5]=b4.y; bias[6]=b4.z; bias[7]=b4.w;
  }

  int t0 = wave * 16;
  int b = t0 / 3136;
  int n0 = t0 - b*3136;
  const u16* vbase = vb + ((size_t)b*3136)*512 + c0;

  for (int ti = 0; ti < 16; ti++) {
    int n = n0 + ti;
    int y = n / 56, x = n - y*56;
    size_t toff = ((size_t)b*3136 + n)*512 + c0;
    float acc[8];
    {
      uint4 uo = *(const uint4*)(io + toff);
      u32 uu[4] = {uo.x, uo.y, uo.z, uo.w};
      #pragma unroll
      for (int e = 0; e < 4; e++) {
        acc[2*e+0] = bflo(uu[e]) + bias[2*e+0];
        acc[2*e+1] = bfhi(uu[e]) + bias[2*e+1];
      }
    }
    #pragma unroll
    for (int dy = 0; dy < 3; dy++) {
      int yy = y + dy - 1;
      if (yy < 0 || yy > 55) continue;
      #pragma unroll
      for (int dx = 0; dx < 3; dx++) {
        int xx = x + dx - 1;
        if (xx < 0 || xx > 55) continue;
        uint4 uv = *(const uint4*)(vbase + ((size_t)(yy*56 + xx) << 9));
        u32 uu[4] = {uv.x, uv.y, uv.z, uv.w};
        const float* wr = wt[dy*3 + dx];
        #pragma unroll
        for (int e = 0; e < 4; e++) {
          acc[2*e+0] += bflo(uu[e]) * wr[2*e+0];
          acc[2*e+1] += bfhi(uu[e]) * wr[2*e+1];
        }
      }
    }
    uint4 pk;
    pk.x = (u32)f2bf(acc[0]) | ((u32)f2bf(acc[1]) << 16);
    pk.y = (u32)f2bf(acc[2]) | ((u32)f2bf(acc[3]) << 16);
    pk.z = (u32)f2bf(acc[4]) | ((u32)f2bf(acc[5]) << 16);
    pk.w = (u32)f2bf(acc[6]) | ((u32)f2bf(acc[7]) << 16);
    *(uint4*)(io + toff) = pk;
  }
}

extern "C" void kernel_launch(void* const* d_in, const int* in_sizes, int n_in,
                              void* d_out, int out_size, void* d_ws, size_t ws_size,
                              hipStream_t stream)
{
  const float* x       = (const float*)d_in[0];
  const float* w_qkv   = (const float*)d_in[1];
  const float* w_proj  = (const float*)d_in[2];
  const float* b_proj  = (const float*)d_in[3];
  const float* w_dwc   = (const float*)d_in[4];
  const float* b_dwc   = (const float*)d_in[5];
  const float* an_bias = (const float*)d_in[6];
  const float* na_bias = (const float*)d_in[7];
  const float* ah_bias = (const float*)d_in[8];
  const float* aw_bias = (const float*)d_in[9];
  const float* ha_bias = (const float*)d_in[10];
  const float* wa_bias = (const float*)d_in[11];
  const float* ca_bias = (const float*)d_in[12];

  if (ws_size < 210000000u) return;

  char* p = (char*)d_ws;
  u16* regA   = (u16*)p;  p += 51380224;   // xb -> {PBIT,ABI,pav,psum,avTg}
  u16* qb     = (u16*)p;  p += 51380224;
  u16* kb     = (u16*)p;  p += 51380224;   // k -> attn_out (aout) after stage1
  u16* vb     = (u16*)p;  p += 51380224;
  u16* wqkvb  = (u16*)p;  p += 1572864;
  u16* wprojb = (u16*)p;  p += 524288;
  u16* agentb = (u16*)p;  p += 1048576;    // 16 x 64(padded) x 512 bf16
  float* PB   = (float*)p; p += 307456;
  float* AB   = (float*)p; p += 309248;

  float* PBIT = (float*)((char*)regA);                  // 6,422,528
  float* ABI  = (float*)((char*)regA + 6422528);        // 6,422,528
  float* pav  = (float*)((char*)regA + 12845056);       // 14,680,064
  float* psum = (float*)((char*)regA + 27525120);       //    229,376
  u16*   avTg = (u16*)  ((char*)regA + 27754496);       //  1,179,648
  u16*   aout = kb;

  cast_bf16<<<25088, 256, 0, stream>>>(x, regA, 6422528);
  cast_bf16<<<768,   256, 0, stream>>>(w_qkv, wqkvb, 196608);
  cast_bf16<<<256,   256, 0, stream>>>(w_proj, wprojb, 65536);

  gemm256<<<dim3(196,6), 512, 0, stream>>>(regA, wqkvb, 512, 0, qb, kb, vb, nullptr, nullptr);
  pool_q<<<256, 256, 0, stream>>>(qb, agentb);
  bias_pre<<<602, 256, 0, stream>>>(an_bias, na_bias, ah_bias, aw_bias, ha_bias, wa_bias, ca_bias, PB, AB);
  bias_expand2<<<12544, 256, 0, stream>>>(PB, AB, PBIT, ABI);
  stage1_mfma<<<dim3(128,7), 256, 0, stream>>>(kb, vb, agentb, PBIT, pav, psum);
  reduce_agv<<<2048, 256, 0, stream>>>(pav, psum, avTg);
  stage2_mfma<<<dim3(128,7), 256, 0, stream>>>(qb, agentb, avTg, ABI, aout);
  dwc_add2<<<784, 256, 0, stream>>>(vb, w_dwc, b_dwc, aout);
  gemm256<<<dim3(196,2), 512, 0, stream>>>(aout, wprojb, 512, 1, nullptr, nullptr, nullptr,
                                           (float*)d_out, b_proj);
}